// Round 2
// baseline (3760.297 us; speedup 1.0000x reference)
//
#include <hip/hip_runtime.h>
#include <hip/hip_bf16.h>
#include <math.h>

#define TT 1024
#define BB 256
#define LOG2PI 1.8378770664093453f

__device__ __forceinline__ float sigmoid_f(float x) {
    return 1.f / (1.f + __expf(-x));
}
__device__ __forceinline__ float tanh_f(float x) {
    // tanh(x) = 1 - 2/(exp(2x)+1); correct saturation at +/-inf
    return 1.f - 2.f / (__expf(2.f*x) + 1.f);
}

// ---------------------------------------------------------------------------
// G[row][c] = X[row,:] . W[c,:] + bias1[c] + bias2[c]
// W is (512, K) row-major. 64-row x 64-col tile per 256-thread block.
// LDS layouts padded to 65 floats/row -> conflict-free scalar reads.
// ---------------------------------------------------------------------------
template<int K, bool CONCAT>
__global__ __launch_bounds__(256) void gemm_ih_kernel(
    const float* __restrict__ Xa, const float* __restrict__ Xb,
    const float* __restrict__ W,
    const float* __restrict__ bias1, const float* __restrict__ bias2,
    float* __restrict__ Gout)
{
    __shared__ float Ws[64*65];
    __shared__ float Xs[64*65];
    const int tid   = threadIdx.x;
    const int chunk = blockIdx.x & 7;   // 8 col chunks of 64 (512 cols)
    const int rtile = blockIdx.x >> 3;
    const int row0  = rtile * 64;
    const int c0    = chunk * 64;
    const int cgrp  = tid & 15;         // cols: cgrp + 16*i (strided -> no conflicts)
    const int rgrp  = tid >> 4;         // rows: rgrp*4 + rr

    float acc[4][4] = {};

    for (int k0 = 0; k0 < K; k0 += 64) {
        const int kt = (K - k0 < 64) ? (K - k0) : 64;
        if (kt == 64) {
            for (int e = tid; e < 64*64; e += 256) {
                int c = e >> 6, kk = e & 63;
                Ws[c*65 + kk] = W[(size_t)(c0 + c)*K + k0 + kk];
            }
            for (int e = tid; e < 64*64; e += 256) {
                int r = e >> 6, kk = e & 63;
                float v;
                if (CONCAT) v = Xa[(size_t)(row0 + r)*64 + kk];   // k0==0 for this path
                else        v = Xa[(size_t)(row0 + r)*K + k0 + kk];
                Xs[r*65 + kk] = v;
            }
        } else {
            for (int e = tid; e < 64*kt; e += 256) {
                int c = e / kt, kk = e - c*kt;
                Ws[c*65 + kk] = W[(size_t)(c0 + c)*K + k0 + kk];
            }
            for (int e = tid; e < 64*kt; e += 256) {
                int r = e / kt, kk = e - r*kt;
                float v;
                if (CONCAT) {
                    int k = k0 + kk;
                    v = (k < 64) ? Xa[(size_t)(row0 + r)*64 + k] : Xb[row0 + r];
                } else {
                    v = Xa[(size_t)(row0 + r)*K + k0 + kk];
                }
                Xs[r*65 + kk] = v;
            }
        }
        __syncthreads();
        #pragma unroll 4
        for (int kk = 0; kk < kt; ++kk) {
            float xv[4], wv[4];
            #pragma unroll
            for (int rr = 0; rr < 4; ++rr) xv[rr] = Xs[(rgrp*4 + rr)*65 + kk];
            #pragma unroll
            for (int i = 0; i < 4; ++i)  wv[i]  = Ws[(cgrp + 16*i)*65 + kk];
            #pragma unroll
            for (int rr = 0; rr < 4; ++rr)
                #pragma unroll
                for (int i = 0; i < 4; ++i)
                    acc[rr][i] = fmaf(xv[rr], wv[i], acc[rr][i]);
        }
        __syncthreads();
    }
    #pragma unroll
    for (int i = 0; i < 4; ++i) {
        const int c = c0 + cgrp + 16*i;
        const float bb = bias1[c] + bias2[c];
        #pragma unroll
        for (int rr = 0; rr < 4; ++rr) {
            const int r = row0 + rgrp*4 + rr;
            Gout[(size_t)r*512 + c] = acc[rr][i] + bb;
        }
    }
}

// ---------------------------------------------------------------------------
// Sequential LSTM pass over `steps` timesteps (one chunk). One block per batch
// element, 1024 threads. thread(half=tid>>9, j=tid&511) holds
// w_hh[j][half*64 .. +64) in registers. h in LDS (wave-uniform broadcast
// reads). G row prefetched 1 step ahead. State carried via h_state/c_state.
// ---------------------------------------------------------------------------
__global__ __launch_bounds__(1024) void lstm_pass_kernel(
    const float* __restrict__ G,       // (steps*B, 512) chunk-local, incl. biases
    const float* __restrict__ wh,      // (512,128)
    float* __restrict__ h_state,       // (B,128) in/out
    float* __restrict__ c_state,       // (B,128) in/out
    float* __restrict__ h_all,         // (steps*B,128) chunk-local
    int steps)
{
    const int b    = blockIdx.x;
    const int tid  = threadIdx.x;
    const int half = tid >> 9;
    const int j    = tid & 511;

    __shared__ float h_lds[128];
    __shared__ float partial[2][512];

    float w[64];
    {
        const float* wr = wh + (size_t)j*128 + half*64;
        #pragma unroll
        for (int kk = 0; kk < 64; ++kk) w[kk] = wr[kk];
    }
    float c_reg = 0.f;
    if (tid < 128) {
        h_lds[tid] = h_state[b*128 + tid];
        c_reg      = c_state[b*128 + tid];
    }
    float g0=0.f, g1=0.f, g2=0.f, g3=0.f;
    if (tid < 128) {
        const float* gr = G + (size_t)b*512;   // row t=0
        g0 = gr[tid]; g1 = gr[128+tid]; g2 = gr[256+tid]; g3 = gr[384+tid];
    }
    __syncthreads();

    for (int t = 0; t < steps; ++t) {
        // prefetch next G row (hides HBM/L2 latency under the FMA phase)
        float n0=0.f, n1=0.f, n2=0.f, n3=0.f;
        if (tid < 128 && t + 1 < steps) {
            const float* gn = G + ((size_t)(t+1)*BB + b)*512;
            n0 = gn[tid]; n1 = gn[128+tid]; n2 = gn[256+tid]; n3 = gn[384+tid];
        }
        float accv = 0.f;
        const float* hb = h_lds + half*64;
        #pragma unroll
        for (int kk = 0; kk < 64; ++kk) accv = fmaf(w[kk], hb[kk], accv);
        partial[half][j] = accv;
        __syncthreads();
        if (tid < 128) {
            float gi = partial[0][tid]     + partial[1][tid]     + g0;
            float gf = partial[0][128+tid] + partial[1][128+tid] + g1;
            float gg = partial[0][256+tid] + partial[1][256+tid] + g2;
            float go = partial[0][384+tid] + partial[1][384+tid] + g3;
            float iv = sigmoid_f(gi);
            float fv = sigmoid_f(gf);
            float gv = tanh_f(gg);
            float ov = sigmoid_f(go);
            c_reg = fmaf(fv, c_reg, iv*gv);
            float hv = ov * tanh_f(c_reg);
            h_lds[tid] = hv;
            h_all[((size_t)t*BB + b)*128 + tid] = hv;
        }
        g0=n0; g1=n1; g2=n2; g3=n3;
        __syncthreads();
    }
    if (tid < 128) {
        h_state[b*128 + tid] = h_lds[tid];
        c_state[b*128 + tid] = c_reg;
    }
}

// ---------------------------------------------------------------------------
__global__ __launch_bounds__(256) void init_state_kernel(
    const float* __restrict__ h0, const float* __restrict__ c0,
    float* __restrict__ h_state, float* __restrict__ c_state)
{
    const int idx = blockIdx.x*256 + threadIdx.x;   // 0 .. 2*B*128-1
    h_state[idx] = h0[idx];
    c_state[idx] = c0[idx];
}

// ---------------------------------------------------------------------------
// Goal decoder: latents(64) -> 64 relu -> 32 ; goals + log_prob_goals
// ---------------------------------------------------------------------------
__global__ __launch_bounds__(256) void dec_goal_kernel(
    const float* __restrict__ h2,
    const float* __restrict__ geps,
    const float* __restrict__ w1, const float* __restrict__ b1,
    const float* __restrict__ w2, const float* __restrict__ b2,
    float* __restrict__ out_goals, float* __restrict__ out_lpg)
{
    __shared__ float W1[64*64];
    __shared__ float W2[32*64];
    __shared__ float B1[64];
    __shared__ float B2[32];
    const int tid = threadIdx.x;
    for (int e = tid; e < 64*64; e += 256) W1[e] = w1[e];
    for (int e = tid; e < 32*64; e += 256) W2[e] = w2[e];
    if (tid < 64) B1[tid] = b1[tid];
    if (tid < 32) B2[tid] = b2[tid];
    __syncthreads();

    const size_t row = (size_t)blockIdx.x*256 + tid;
    const float* xr = h2 + row*128;   // first 64 = latents

    float hid[64];
    #pragma unroll
    for (int jj = 0; jj < 64; ++jj) hid[jj] = B1[jj];
    for (int k = 0; k < 64; k += 4) {
        float4 xv = *(const float4*)(xr + k);
        #pragma unroll
        for (int jj = 0; jj < 64; ++jj) {
            float s = hid[jj];
            s = fmaf(W1[jj*64 + k],     xv.x, s);
            s = fmaf(W1[jj*64 + k + 1], xv.y, s);
            s = fmaf(W1[jj*64 + k + 2], xv.z, s);
            s = fmaf(W1[jj*64 + k + 3], xv.w, s);
            hid[jj] = s;
        }
    }
    #pragma unroll
    for (int jj = 0; jj < 64; ++jj) hid[jj] = fmaxf(hid[jj], 0.f);

    float gm[16];
    #pragma unroll
    for (int jj = 0; jj < 16; ++jj) {
        float s = B2[jj];
        #pragma unroll
        for (int k = 0; k < 64; ++k) s = fmaf(W2[jj*64 + k], hid[k], s);
        gm[jj] = 100.f * tanh_f(0.001f * s);
    }
    float ge[16];
    #pragma unroll
    for (int d = 0; d < 16; d += 4) {
        float4 v = *(const float4*)(geps + row*16 + d);
        ge[d]=v.x; ge[d+1]=v.y; ge[d+2]=v.z; ge[d+3]=v.w;
    }
    float lsum = 0.f;
    float goalv[16];
    #pragma unroll
    for (int jj = 0; jj < 16; ++jj) {
        float s = B2[16 + jj];
        #pragma unroll
        for (int k = 0; k < 64; ++k) s = fmaf(W2[(16+jj)*64 + k], hid[k], s);
        float gs   = tanh_f(s);
        float gvar = fmaf(gs, gs, 0.001f);
        float goal = fmaf(sqrtf(gvar), ge[jj], gm[jj]);
        goalv[jj] = goal;
        float dd = goal - gm[jj];
        lsum += dd*dd/gvar + __logf(gvar);
    }
    #pragma unroll
    for (int d = 0; d < 16; d += 4) {
        float4 v = make_float4(goalv[d], goalv[d+1], goalv[d+2], goalv[d+3]);
        *(float4*)(out_goals + row*16 + d) = v;
    }
    out_lpg[row] = -0.5f*(lsum + 16.f*LOG2PI);
}

// ---------------------------------------------------------------------------
// Action + value decoder: goal_obs(80) -> [ad: 80 relu -> 16] and [vd: 80 relu -> 1]
// ---------------------------------------------------------------------------
__global__ __launch_bounds__(256) void dec_av_kernel(
    const float* __restrict__ goals,
    const float* __restrict__ obs,
    const float* __restrict__ aeps,
    const float* __restrict__ aw1, const float* __restrict__ ab1,
    const float* __restrict__ aw2, const float* __restrict__ ab2,
    const float* __restrict__ vw1, const float* __restrict__ vb1,
    const float* __restrict__ vw2, const float* __restrict__ vb2,
    float* __restrict__ out_actions, float* __restrict__ out_lpa,
    float* __restrict__ out_values)
{
    __shared__ float AW1[80*80];
    __shared__ float VW1[80*80];
    __shared__ float AW2[16*80];
    __shared__ float VW2[80];
    __shared__ float AB1[80];
    __shared__ float VB1[80];
    __shared__ float AB2[16];
    const int tid = threadIdx.x;
    for (int e = tid; e < 80*80; e += 256) { AW1[e] = aw1[e]; VW1[e] = vw1[e]; }
    for (int e = tid; e < 16*80; e += 256) AW2[e] = aw2[e];
    if (tid < 80) { VW2[tid] = vw2[tid]; AB1[tid] = ab1[tid]; VB1[tid] = vb1[tid]; }
    if (tid < 16) AB2[tid] = ab2[tid];
    __syncthreads();

    const size_t row = (size_t)blockIdx.x*256 + tid;

    // ----- ad hidden -----
    float hid[80];
    #pragma unroll
    for (int jj = 0; jj < 80; ++jj) hid[jj] = AB1[jj];
    for (int k = 0; k < 80; k += 4) {
        float4 xv;
        if (k < 16) xv = *(const float4*)(goals + row*16 + k);
        else        xv = *(const float4*)(obs + row*64 + (k - 16));
        #pragma unroll
        for (int jj = 0; jj < 80; ++jj) {
            float s = hid[jj];
            s = fmaf(AW1[jj*80 + k],     xv.x, s);
            s = fmaf(AW1[jj*80 + k + 1], xv.y, s);
            s = fmaf(AW1[jj*80 + k + 2], xv.z, s);
            s = fmaf(AW1[jj*80 + k + 3], xv.w, s);
            hid[jj] = s;
        }
    }
    #pragma unroll
    for (int jj = 0; jj < 80; ++jj) hid[jj] = fmaxf(hid[jj], 0.f);

    float am[8], asd[8];
    #pragma unroll
    for (int jj = 0; jj < 8; ++jj) {
        float s = AB2[jj];
        #pragma unroll
        for (int k = 0; k < 80; ++k) s = fmaf(AW2[jj*80 + k], hid[k], s);
        am[jj] = s;
    }
    #pragma unroll
    for (int jj = 0; jj < 8; ++jj) {
        float s = AB2[8 + jj];
        #pragma unroll
        for (int k = 0; k < 80; ++k) s = fmaf(AW2[(8+jj)*80 + k], hid[k], s);
        asd[jj] = s;
    }

    float ae[8];
    #pragma unroll
    for (int d = 0; d < 8; d += 4) {
        float4 v = *(const float4*)(aeps + row*8 + d);
        ae[d]=v.x; ae[d+1]=v.y; ae[d+2]=v.z; ae[d+3]=v.w;
    }
    float lsum = 0.f;
    float actv[8];
    #pragma unroll
    for (int d = 0; d < 8; ++d) {
        float avar = fmaf(asd[d], asd[d], 0.001f);
        float act  = fmaf(sqrtf(avar), ae[d], am[d]);
        actv[d] = act;
        float dd = act - am[d];
        lsum += dd*dd/avar + __logf(avar);
    }
    #pragma unroll
    for (int d = 0; d < 8; d += 4) {
        float4 v = make_float4(actv[d], actv[d+1], actv[d+2], actv[d+3]);
        *(float4*)(out_actions + row*8 + d) = v;
    }
    out_lpa[row] = -0.5f*(lsum + 8.f*LOG2PI);

    // ----- vd -----
    float vh[80];
    #pragma unroll
    for (int jj = 0; jj < 80; ++jj) vh[jj] = VB1[jj];
    for (int k = 0; k < 80; k += 4) {
        float4 xv;
        if (k < 16) xv = *(const float4*)(goals + row*16 + k);
        else        xv = *(const float4*)(obs + row*64 + (k - 16));
        #pragma unroll
        for (int jj = 0; jj < 80; ++jj) {
            float s = vh[jj];
            s = fmaf(VW1[jj*80 + k],     xv.x, s);
            s = fmaf(VW1[jj*80 + k + 1], xv.y, s);
            s = fmaf(VW1[jj*80 + k + 2], xv.z, s);
            s = fmaf(VW1[jj*80 + k + 3], xv.w, s);
            vh[jj] = s;
        }
    }
    float v = vb2[0];
    #pragma unroll
    for (int jj = 0; jj < 80; ++jj) v = fmaf(VW2[jj], fmaxf(vh[jj], 0.f), v);
    out_values[row] = v;
}

// ---------------------------------------------------------------------------
// lp decoder: full_lat_obs(192) -> 192 relu -> 1. 4 lanes per item,
// quad reduce via shfl_xor, w1 staged in LDS in 3 chunks of 64 rows.
// ---------------------------------------------------------------------------
__global__ __launch_bounds__(256) void dec_lpv_kernel(
    const float* __restrict__ h2,
    const float* __restrict__ obs,
    const float* __restrict__ w1, const float* __restrict__ b1,
    const float* __restrict__ w2, const float* __restrict__ b2,
    float* __restrict__ out_lpv)
{
    __shared__ float W1s[64*192];
    __shared__ float B1[192];
    __shared__ float W2[192];
    const int tid = threadIdx.x;
    const int l = tid & 3;
    const size_t item = (size_t)blockIdx.x*64 + (tid >> 2);
    if (tid < 192) { B1[tid] = b1[tid]; W2[tid] = w2[tid]; }

    float x[48];
    #pragma unroll
    for (int q = 0; q < 12; ++q) {
        int gk = l*48 + q*4;
        float4 v;
        if (gk < 128) v = *(const float4*)(h2 + item*128 + gk);
        else          v = *(const float4*)(obs + item*64 + (gk - 128));
        x[q*4]=v.x; x[q*4+1]=v.y; x[q*4+2]=v.z; x[q*4+3]=v.w;
    }

    float acc = 0.f;
    for (int j0 = 0; j0 < 192; j0 += 64) {
        __syncthreads();
        for (int e = tid; e < 64*192; e += 256) W1s[e] = w1[(size_t)j0*192 + e];
        __syncthreads();
        for (int jj = 0; jj < 64; ++jj) {
            const float* wr = W1s + jj*192 + l*48;
            float p = 0.f;
            #pragma unroll
            for (int q = 0; q < 12; ++q) {
                float4 wv = *(const float4*)(wr + q*4);
                p = fmaf(wv.x, x[q*4],     p);
                p = fmaf(wv.y, x[q*4 + 1], p);
                p = fmaf(wv.z, x[q*4 + 2], p);
                p = fmaf(wv.w, x[q*4 + 3], p);
            }
            p += __shfl_xor(p, 1);
            p += __shfl_xor(p, 2);
            float h = fmaxf(p + B1[j0 + jj], 0.f);
            acc = fmaf(W2[j0 + jj], h, acc);
        }
    }
    if (l == 0) out_lpv[item] = acc + b2[0];
}

// ---------------------------------------------------------------------------
extern "C" void kernel_launch(void* const* d_in, const int* in_sizes, int n_in,
                              void* d_out, int out_size, void* d_ws, size_t ws_size,
                              hipStream_t stream)
{
    (void)in_sizes; (void)n_in; (void)out_size;

    const float* obs    = (const float*)d_in[0];
    const float* lps    = (const float*)d_in[1];
    const float* geps   = (const float*)d_in[2];
    const float* aeps   = (const float*)d_in[3];
    const float* h0     = (const float*)d_in[4];
    const float* c0     = (const float*)d_in[5];
    const float* w_ih0  = (const float*)d_in[6];
    const float* b_ih0  = (const float*)d_in[7];
    const float* w_hh0  = (const float*)d_in[8];
    const float* b_hh0  = (const float*)d_in[9];
    const float* w_ih1  = (const float*)d_in[10];
    const float* b_ih1  = (const float*)d_in[11];
    const float* w_hh1  = (const float*)d_in[12];
    const float* b_hh1  = (const float*)d_in[13];
    const float* gd_w1  = (const float*)d_in[14];
    const float* gd_b1  = (const float*)d_in[15];
    const float* gd_w2  = (const float*)d_in[16];
    const float* gd_b2  = (const float*)d_in[17];
    const float* ad_w1  = (const float*)d_in[18];
    const float* ad_b1  = (const float*)d_in[19];
    const float* ad_w2  = (const float*)d_in[20];
    const float* ad_b2  = (const float*)d_in[21];
    const float* vd_w1  = (const float*)d_in[22];
    const float* vd_b1  = (const float*)d_in[23];
    const float* vd_w2  = (const float*)d_in[24];
    const float* vd_b2  = (const float*)d_in[25];
    const float* lpd_w1 = (const float*)d_in[26];
    const float* lpd_b1 = (const float*)d_in[27];
    const float* lpd_w2 = (const float*)d_in[28];
    const float* lpd_b2 = (const float*)d_in[29];

    float* out         = (float*)d_out;
    float* out_actions = out;                 // (T,B,8)
    float* out_lpa     = out + 2097152;       // (T,B)
    float* out_goals   = out + 2359296;       // (T,B,16)
    float* out_lpg     = out + 6553600;       // (T,B)
    float* out_values  = out + 6815744;       // (T,B,1)
    float* out_lpv     = out + 7077888;       // (T,B,1)

    // --- adaptive time-chunking to fit ws_size ---
    // per chunk of C steps: G (C*B*512) + h1 (C*B*128) + h2 (C*B*128) floats
    // plus persistent state: h_state + c_state (2 layers * B * 128 each)
    const size_t STATE_ELEMS = 2ull * BB * 128;            // per h or c
    const size_t state_bytes = 2ull * STATE_ELEMS * 4;     // h + c
    int C = 0;
    for (int c = TT; c >= 8; c >>= 1) {
        size_t need = (size_t)c * BB * (512 + 128 + 128) * 4 + state_bytes;
        if (need <= ws_size) { C = c; break; }
    }
    if (C == 0) return;   // cannot run — outputs stay zero (visible in bench)
    const int nchunks = TT / C;

    float* Gc      = (float*)d_ws;
    float* h1c     = Gc  + (size_t)C * BB * 512;
    float* h2c     = h1c + (size_t)C * BB * 128;
    float* h_state = h2c + (size_t)C * BB * 128;
    float* c_state = h_state + STATE_ELEMS;

    const dim3 blk(256);
    init_state_kernel<<<dim3((int)(STATE_ELEMS/256)), blk, 0, stream>>>(
        h0, c0, h_state, c_state);

    for (int ch = 0; ch < nchunks; ++ch) {
        const size_t crow0 = (size_t)ch * C * BB;
        const int rows = C * BB;

        gemm_ih_kernel<65, true><<<dim3((rows/64)*8), blk, 0, stream>>>(
            obs + crow0*64, lps + crow0, w_ih0, b_ih0, b_hh0, Gc);

        lstm_pass_kernel<<<dim3(BB), dim3(1024), 0, stream>>>(
            Gc, w_hh0, h_state, c_state, h1c, C);

        gemm_ih_kernel<128, false><<<dim3((rows/64)*8), blk, 0, stream>>>(
            h1c, nullptr, w_ih1, b_ih1, b_hh1, Gc);

        lstm_pass_kernel<<<dim3(BB), dim3(1024), 0, stream>>>(
            Gc, w_hh1, h_state + BB*128, c_state + BB*128, h2c, C);

        dec_goal_kernel<<<dim3(rows/256), blk, 0, stream>>>(
            h2c, geps + crow0*16, gd_w1, gd_b1, gd_w2, gd_b2,
            out_goals + crow0*16, out_lpg + crow0);

        dec_av_kernel<<<dim3(rows/256), blk, 0, stream>>>(
            out_goals + crow0*16, obs + crow0*64, aeps + crow0*8,
            ad_w1, ad_b1, ad_w2, ad_b2, vd_w1, vd_b1, vd_w2, vd_b2,
            out_actions + crow0*8, out_lpa + crow0, out_values + crow0);

        dec_lpv_kernel<<<dim3(rows/64), blk, 0, stream>>>(
            h2c, obs + crow0*64, lpd_w1, lpd_b1, lpd_w2, lpd_b2,
            out_lpv + crow0);
    }
}